// Round 9
// baseline (259.975 us; speedup 1.0000x reference)
//
#include <hip/hip_runtime.h>
#include <hip/hip_bf16.h>
#include <hip/hip_cooperative_groups.h>

namespace cg = cooperative_groups;

// Problem constants (match reference)
#define B_   8
#define NQ_  64     // N_CANDS
#define CTX_ 512    // CTX_LEN
#define DC_  512    // CONTEXT_SIZE
#define DQ_  512    // QUERY_SIZE
#define H_   256    // HIDDEN
#define EPS_ 1e-5f

using short8  = __attribute__((ext_vector_type(8))) short;  // 8 bf16 (4 VGPRs)
using floatx4 = __attribute__((ext_vector_type(4))) float;  // MFMA acc

// 2 fp32 -> packed bf16x2 via v_cvt_pk_bf16_f32 (single instruction on gfx950)
__device__ __forceinline__ unsigned pk2(float x, float y) {
    union { __hip_bfloat162 h; unsigned u; } c;
    c.h = __float22bfloat162_rn(make_float2(x, y));
    return c.u;
}
// 8 fp32 (two float4) -> 16B packed bf16
__device__ __forceinline__ uint4 cvt8u(float4 a, float4 b) {
    uint4 r;
    r.x = pk2(a.x, a.y); r.y = pk2(a.z, a.w);
    r.z = pk2(b.x, b.y); r.w = pk2(b.z, b.w);
    return r;
}

// LDS shared across phases (sequential use, separated by barriers)
union SmemU {
    struct { unsigned short As[32][72]; unsigned short Bs[64][72]; } g; // 13.8 KB
    struct { float ecs[64][68]; float redS[4]; } s;                     // 17.4 KB
    struct { float invs[8]; float pc[3][64][8]; } o;                    //  6.2 KB
};

// ---------------------------------------------------------------------------
// Phase G job: one 32Mx64N bf16-MFMA tile of either input GEMM (identical math
// to the R6 gemm_exp, which passed). Epilogue: exp(2*(acc+bias)).
// ---------------------------------------------------------------------------
__device__ __forceinline__ void gemm_job(
    SmemU& sm, int rt, int ct, int t,
    const float* __restrict__ ctx, const float* __restrict__ query,
    const float* __restrict__ W_c, const float* __restrict__ b_c,
    const float* __restrict__ W_q,
    float* __restrict__ Ec, float* __restrict__ Eq)
{
    const float* A; const float* W; const float* bias; float* outp; int row0;
    if (rt < 128) { A = ctx;   W = W_c; bias = b_c;     outp = Ec; row0 = rt * 32; }
    else          { A = query; W = W_q; bias = nullptr; outp = Eq; row0 = (rt - 128) * 32; }

    const int col0 = ct * 64;
    const int wave = t >> 6;
    const int lane = t & 63;
    const int m  = lane & 15;
    const int kq = lane >> 4;
    const int mh = wave >> 1;      // M-half: rows mh*16..+16
    const int nh = wave & 1;       // N-half: cols nh*32..+32

    const int sr = t >> 3, ss = t & 7;
    const float* gA  = A + (size_t)(row0 + sr) * 512 + ss * 8;
    const float* gB0 = W + (size_t)(col0 + sr) * 512 + ss * 8;
    const float* gB1 = W + (size_t)(col0 + 32 + sr) * 512 + ss * 8;
    unsigned short* lA  = &sm.g.As[sr][ss * 8];
    unsigned short* lB0 = &sm.g.Bs[sr][ss * 8];
    unsigned short* lB1 = &sm.g.Bs[32 + sr][ss * 8];

    floatx4 acc[2] = {};
    float4 pA0, pA1, pB00, pB01, pB10, pB11;

    pA0  = *(const float4*)(gA);       pA1  = *(const float4*)(gA + 4);
    pB00 = *(const float4*)(gB0);      pB01 = *(const float4*)(gB0 + 4);
    pB10 = *(const float4*)(gB1);      pB11 = *(const float4*)(gB1 + 4);

    for (int s = 0; s < 8; ++s) {
        __syncthreads();               // readers of previous step done
        *(uint4*)lA  = cvt8u(pA0, pA1);
        *(uint4*)lB0 = cvt8u(pB00, pB01);
        *(uint4*)lB1 = cvt8u(pB10, pB11);
        __syncthreads();

        if (s < 7) {                   // prefetch next step (overlaps compute)
            const int k = (s + 1) * 64;
            pA0  = *(const float4*)(gA + k);   pA1  = *(const float4*)(gA + k + 4);
            pB00 = *(const float4*)(gB0 + k);  pB01 = *(const float4*)(gB0 + k + 4);
            pB10 = *(const float4*)(gB1 + k);  pB11 = *(const float4*)(gB1 + k + 4);
        }

        #pragma unroll
        for (int kc = 0; kc < 2; ++kc) {
            short8 af = *(const short8*)&sm.g.As[mh * 16 + m][kc * 32 + kq * 8];
            short8 b0 = *(const short8*)&sm.g.Bs[nh * 32 +      m][kc * 32 + kq * 8];
            short8 b1 = *(const short8*)&sm.g.Bs[nh * 32 + 16 + m][kc * 32 + kq * 8];
            acc[0] = __builtin_amdgcn_mfma_f32_16x16x32_bf16(af, b0, acc[0], 0, 0, 0);
            acc[1] = __builtin_amdgcn_mfma_f32_16x16x32_bf16(af, b1, acc[1], 0, 0, 0);
        }
    }

    #pragma unroll
    for (int j = 0; j < 2; ++j) {
        const int col = col0 + nh * 32 + j * 16 + m;
        const float bb = bias ? bias[col] : 0.f;
        #pragma unroll
        for (int i = 0; i < 4; ++i) {
            const int row = row0 + mh * 16 + kq * 4 + i;
            outp[(size_t)row * H_ + col] = __expf(2.f * (acc[j][i] + bb));
        }
    }
}

// ---------------------------------------------------------------------------
// Fused cooperative kernel: Phase G (both GEMMs, 576 jobs over 512 blocks) ->
// grid.sync -> Phase S (scoring + partial denominators) -> grid.sync ->
// Phase O (inv-denoms + wout + weighted context sum).
// ---------------------------------------------------------------------------
__global__ __launch_bounds__(256, 2) void attn_all(
    const float* __restrict__ ctx, const float* __restrict__ query,
    const float* __restrict__ W_c, const float* __restrict__ b_c,
    const float* __restrict__ W_q, const float* __restrict__ W_o,
    const float* __restrict__ b_o_p, const float* __restrict__ mask,
    float* __restrict__ Ec, float* __restrict__ Eq,
    float* __restrict__ eout, float* __restrict__ eoutT,
    float* __restrict__ denomP,
    float* __restrict__ out, float* __restrict__ wout)
{
    __shared__ SmemU sm;
    cg::grid_group grid = cg::this_grid();
    const int blk = blockIdx.x;
    const int t   = threadIdx.x;

    // ================= Phase G: input GEMMs =================
    gemm_job(sm, blk >> 2, blk & 3, t, ctx, query, W_c, b_c, W_q, Ec, Eq);
    if (blk < 64)   // 64 query-GEMM tiles as second jobs
        gemm_job(sm, 128 + (blk >> 2), blk & 3, t, ctx, query, W_c, b_c, W_q, Ec, Eq);

    grid.sync();

    // ================= Phase S: scoring =================
    {
        const int b  = blk & 7;          // XCD swizzle
        const int ctile = (blk >> 3) & 7;
        const int qg = blk >> 6;

        float S = W_o[t];                // Sum(W_o) via butterfly
        #pragma unroll
        for (int k = 1; k < 64; k <<= 1) S += __shfl_xor(S, k);
        if ((t & 63) == 0) sm.s.redS[t >> 6] = S;

        const int cl = t & 63;
        const int qi = __builtin_amdgcn_readfirstlane(t >> 6);  // wave's q-pair
        const int c0 = ctile * 64;
        const float* ec_tile = Ec + (size_t)(b * CTX_ + c0) * H_;
        const int sr = t >> 2, sseg = (t & 3) * 16;
        const float* ssrc = ec_tile + (size_t)sr * H_ + sseg;
        const float* eqa = Eq + (size_t)(b * NQ_ + qg * 8 + qi * 2) * H_; // uniform
        const float* eqc = eqa + H_;                                      // uniform

        float s0 = 0.f, s1 = 0.f;
        for (int hb = 0; hb < 4; ++hb) {
            float4 v0 = *(const float4*)(ssrc + hb * 64);
            float4 v1 = *(const float4*)(ssrc + hb * 64 + 4);
            float4 v2 = *(const float4*)(ssrc + hb * 64 + 8);
            float4 v3 = *(const float4*)(ssrc + hb * 64 + 12);
            __syncthreads();             // prior chunk's compute done (covers redS)
            float* dst = &sm.s.ecs[sr][sseg];
            *(float4*)(dst)     = v0; *(float4*)(dst + 4)  = v1;
            *(float4*)(dst + 8) = v2; *(float4*)(dst + 12) = v3;
            __syncthreads();
            const int ho = hb * 64;
            #pragma unroll
            for (int h4 = 0; h4 < 16; ++h4) {
                float4 ea = *(const float4*)&sm.s.ecs[cl][h4 * 4];
                float4 qa = *(const float4*)(eqa + ho + h4 * 4);   // uniform
                float4 qc = *(const float4*)(eqc + ho + h4 * 4);   // uniform
                float4 w4 = *(const float4*)(W_o + ho + h4 * 4);   // uniform
                s0 += w4.x * __builtin_amdgcn_rcpf(ea.x * qa.x + 1.f);
                s0 += w4.y * __builtin_amdgcn_rcpf(ea.y * qa.y + 1.f);
                s0 += w4.z * __builtin_amdgcn_rcpf(ea.z * qa.z + 1.f);
                s0 += w4.w * __builtin_amdgcn_rcpf(ea.w * qa.w + 1.f);
                s1 += w4.x * __builtin_amdgcn_rcpf(ea.x * qc.x + 1.f);
                s1 += w4.y * __builtin_amdgcn_rcpf(ea.y * qc.y + 1.f);
                s1 += w4.z * __builtin_amdgcn_rcpf(ea.z * qc.z + 1.f);
                s1 += w4.w * __builtin_amdgcn_rcpf(ea.w * qc.w + 1.f);
            }
        }

        const float base = *b_o_p + sm.s.redS[0] + sm.s.redS[1]
                                  + sm.s.redS[2] + sm.s.redS[3];
        const int c = c0 + cl;
        const float mk = mask[b * CTX_ + c];
        const float e0 = mk * __expf(base - 2.f * s0);
        const float e1 = mk * __expf(base - 2.f * s1);
        const int qa_ = b * NQ_ + qg * 8 + qi * 2;
        eout[(size_t)qa_ * CTX_ + c]       = e0;
        eout[(size_t)(qa_ + 1) * CTX_ + c] = e1;
        *(float2*)&eoutT[(((size_t)(b * 8 + qg) * CTX_) + c) * 8 + qi * 2] =
            make_float2(e0, e1);

        // partial denominators: sum e over this 64-c tile (per q)
        float d0 = e0, d1 = e1;
        #pragma unroll
        for (int k = 1; k < 64; k <<= 1) {
            d0 += __shfl_xor(d0, k);
            d1 += __shfl_xor(d1, k);
        }
        if ((t & 63) == 0) {
            const int qb = (b * 8 + qg) * 64;
            denomP[qb + (qi * 2) * 8 + ctile]     = d0;
            denomP[qb + (qi * 2 + 1) * 8 + ctile] = d1;
        }
    }

    grid.sync();

    // ================= Phase O: output =================
    {
        const int b  = blk & 7;
        const int qg = (blk >> 3) & 7;
        const int dq = blk >> 6;           // 0..7: d in [dq*64, +64)

        if (t < 8) {                       // denominators from partials
            const float* dp = denomP + (b * 8 + qg) * 64 + t * 8;
            float s = EPS_;
            #pragma unroll
            for (int j = 0; j < 8; ++j) s += dp[j];
            sm.o.invs[t] = 1.f / s;
        }
        __syncthreads();

        if (dq == 0) {                     // wout = e * inv
            const int qi = t >> 5, cl = t & 31;
            const int q = b * NQ_ + qg * 8 + qi;
            const float inv = sm.o.invs[qi];
            const float* erow = eout + (size_t)q * CTX_;
            #pragma unroll
            for (int k = 0; k < 16; ++k) {
                const int c = cl + 32 * k;
                wout[(size_t)q * CTX_ + c] = erow[c] * inv;
            }
        }

        const int cq4 = __builtin_amdgcn_readfirstlane(t >> 6);   // 0..3 uniform
        const int dt  = t & 63;
        const int d   = dq * 64 + dt;
        const float* cb  = ctx + ((size_t)(b * CTX_) + cq4 * 128) * DC_ + d;
        const float* eoT = eoutT + (((size_t)(b * 8 + qg) * CTX_) + cq4 * 128) * 8;

        float a0=0,a1=0,a2=0,a3=0,a4=0,a5=0,a6=0,a7=0;
        #pragma unroll 4
        for (int c = 0; c < 128; ++c) {
            const float4 eA = *(const float4*)(eoT + c * 8);      // uniform
            const float4 eB = *(const float4*)(eoT + c * 8 + 4);  // uniform
            const float v = cb[(size_t)c * DC_];
            a0 += eA.x * v; a1 += eA.y * v; a2 += eA.z * v; a3 += eA.w * v;
            a4 += eB.x * v; a5 += eB.y * v; a6 += eB.z * v; a7 += eB.w * v;
        }
        if (cq4) {
            float* p = sm.o.pc[cq4 - 1][dt];
            p[0]=a0; p[1]=a1; p[2]=a2; p[3]=a3; p[4]=a4; p[5]=a5; p[6]=a6; p[7]=a7;
        }
        __syncthreads();
        if (cq4 == 0) {
            float r[8] = {a0,a1,a2,a3,a4,a5,a6,a7};
            const int qbase = b * NQ_ + qg * 8;
            #pragma unroll
            for (int j = 0; j < 8; ++j) {
                r[j] = (r[j] + sm.o.pc[0][dt][j] + sm.o.pc[1][dt][j]
                             + sm.o.pc[2][dt][j]) * sm.o.invs[j];
                out[(size_t)(qbase + j) * DC_ + d] = r[j];
            }
        }
    }
}

extern "C" void kernel_launch(void* const* d_in, const int* in_sizes, int n_in,
                              void* d_out, int out_size, void* d_ws, size_t ws_size,
                              hipStream_t stream) {
    const float* query   = (const float*)d_in[0];  // B,NQ,DQ
    const float* context = (const float*)d_in[1];  // B,CTX,DC
    const float* mask    = (const float*)d_in[2];  // B,CTX
    const float* W_c     = (const float*)d_in[3];  // H,DC
    const float* b_c     = (const float*)d_in[4];  // H
    const float* W_q     = (const float*)d_in[5];  // H,DQ
    const float* W_o     = (const float*)d_in[6];  // H
    const float* b_o     = (const float*)d_in[7];  // scalar

    float* out  = (float*)d_out;                   // B,NQ,DC
    float* wout = out + (size_t)B_ * NQ_ * DC_;    // B,NQ,CTX

    float* Ec     = (float*)d_ws;                      // 4 MB: exp(2*res_c)
    float* Eq     = Ec + (size_t)B_ * CTX_ * H_;       // 512 KB: exp(2*res_q)
    float* eout   = Eq + (size_t)B_ * NQ_ * H_;        // 1 MB
    float* eoutT  = eout + (size_t)B_ * NQ_ * CTX_;    // 1 MB
    float* denomP = eoutT + (size_t)B_ * NQ_ * CTX_;   // 16 KB

    void* kargs[] = {
        (void*)&context, (void*)&query, (void*)&W_c, (void*)&b_c,
        (void*)&W_q, (void*)&W_o, (void*)&b_o, (void*)&mask,
        (void*)&Ec, (void*)&Eq, (void*)&eout, (void*)&eoutT, (void*)&denomP,
        (void*)&out, (void*)&wout
    };
    hipError_t err = hipLaunchCooperativeKernel(
        (const void*)attn_all, dim3(512), dim3(256), kargs, 0, stream);
    (void)err;
}

// Round 10
// 114.065 us; speedup vs baseline: 2.2792x; 2.2792x over previous
//
#include <hip/hip_runtime.h>
#include <hip/hip_bf16.h>

// Problem constants (match reference)
#define B_   8
#define NQ_  64     // N_CANDS
#define CTX_ 512    // CTX_LEN
#define DC_  512    // CONTEXT_SIZE
#define DQ_  512    // QUERY_SIZE
#define H_   256    // HIDDEN
#define EPS_ 1e-5f

using short8  = __attribute__((ext_vector_type(8))) short;  // 8 bf16 (4 VGPRs)
using floatx4 = __attribute__((ext_vector_type(4))) float;  // MFMA acc

// 2 fp32 -> packed bf16x2 via v_cvt_pk_bf16_f32 (single instruction on gfx950)
__device__ __forceinline__ unsigned pk2(float x, float y) {
    union { __hip_bfloat162 h; unsigned u; } c;
    c.h = __float22bfloat162_rn(make_float2(x, y));
    return c.u;
}
// 8 fp32 (two float4) -> 16B packed bf16
__device__ __forceinline__ uint4 cvt8u(float4 a, float4 b) {
    uint4 r;
    r.x = pk2(a.x, a.y); r.y = pk2(a.z, a.w);
    r.z = pk2(b.x, b.y); r.w = pk2(b.z, b.w);
    return r;
}

// ---------------------------------------------------------------------------
// Kernel 1 (unchanged from R6, known-good): both input GEMMs via bf16 MFMA,
// LDS-staged with register prefetch. Epilogue: Ec = exp(2*(acc+bias)),
// Eq = exp(2*acc)  (factored-exp: tanh(x) = 1 - 2/(e^{2x}+1)).
// Tile 32Mx64N, BK=64; grid 144x4 = 576 blocks.
// ---------------------------------------------------------------------------
__global__ __launch_bounds__(256) void gemm_exp(
    const float* __restrict__ ctx, const float* __restrict__ query,
    const float* __restrict__ W_c, const float* __restrict__ b_c,
    const float* __restrict__ W_q,
    float* __restrict__ Ec, float* __restrict__ Eq)
{
    __shared__ unsigned short As[32][72];   // 32 rows x 64 bf16 (+8 pad)
    __shared__ unsigned short Bs[64][72];   // 64 rows x 64 bf16 (+8 pad)

    const int rt = blockIdx.x;     // 0..143 (128 ctx + 16 query row-tiles)
    const int ct = blockIdx.y;     // 0..3

    const float* A; const float* W; const float* bias; float* outp; int row0;
    if (rt < 128) { A = ctx;   W = W_c; bias = b_c;     outp = Ec; row0 = rt * 32; }
    else          { A = query; W = W_q; bias = nullptr; outp = Eq; row0 = (rt - 128) * 32; }

    const int col0 = ct * 64;
    const int t    = threadIdx.x;
    const int wave = t >> 6;
    const int lane = t & 63;
    const int m  = lane & 15;
    const int kq = lane >> 4;
    const int mh = wave >> 1;      // M-half: rows mh*16..+16
    const int nh = wave & 1;       // N-half: cols nh*32..+32

    const int sr = t >> 3, ss = t & 7;
    const float* gA  = A + (size_t)(row0 + sr) * 512 + ss * 8;
    const float* gB0 = W + (size_t)(col0 + sr) * 512 + ss * 8;
    const float* gB1 = W + (size_t)(col0 + 32 + sr) * 512 + ss * 8;
    unsigned short* lA  = &As[sr][ss * 8];
    unsigned short* lB0 = &Bs[sr][ss * 8];
    unsigned short* lB1 = &Bs[32 + sr][ss * 8];

    floatx4 acc[2] = {};
    float4 pA0, pA1, pB00, pB01, pB10, pB11;

    pA0  = *(const float4*)(gA);       pA1  = *(const float4*)(gA + 4);
    pB00 = *(const float4*)(gB0);      pB01 = *(const float4*)(gB0 + 4);
    pB10 = *(const float4*)(gB1);      pB11 = *(const float4*)(gB1 + 4);

    for (int s = 0; s < 8; ++s) {
        __syncthreads();
        *(uint4*)lA  = cvt8u(pA0, pA1);
        *(uint4*)lB0 = cvt8u(pB00, pB01);
        *(uint4*)lB1 = cvt8u(pB10, pB11);
        __syncthreads();

        if (s < 7) {
            const int k = (s + 1) * 64;
            pA0  = *(const float4*)(gA + k);   pA1  = *(const float4*)(gA + k + 4);
            pB00 = *(const float4*)(gB0 + k);  pB01 = *(const float4*)(gB0 + k + 4);
            pB10 = *(const float4*)(gB1 + k);  pB11 = *(const float4*)(gB1 + k + 4);
        }

        #pragma unroll
        for (int kc = 0; kc < 2; ++kc) {
            short8 af = *(const short8*)&As[mh * 16 + m][kc * 32 + kq * 8];
            short8 b0 = *(const short8*)&Bs[nh * 32 +      m][kc * 32 + kq * 8];
            short8 b1 = *(const short8*)&Bs[nh * 32 + 16 + m][kc * 32 + kq * 8];
            acc[0] = __builtin_amdgcn_mfma_f32_16x16x32_bf16(af, b0, acc[0], 0, 0, 0);
            acc[1] = __builtin_amdgcn_mfma_f32_16x16x32_bf16(af, b1, acc[1], 0, 0, 0);
        }
    }

    #pragma unroll
    for (int j = 0; j < 2; ++j) {
        const int col = col0 + nh * 32 + j * 16 + m;
        const float bb = bias ? bias[col] : 0.f;
        #pragma unroll
        for (int i = 0; i < 4; ++i) {
            const int row = row0 + mh * 16 + kq * 4 + i;
            outp[(size_t)row * H_ + col] = __expf(2.f * (acc[j][i] + bb));
        }
    }
}

// ---------------------------------------------------------------------------
// Kernel 2: scoring. Grid 1024 = b(8) x ctile(16: 32c) x qgroup(8: 8q) ->
// 4 blocks/CU. Thread owns ONE (c,q):
//   logit = b_o + Sum(W_o) - 2*sum_h W_o[h]/(Ec[c,h]*Eq[q,h]+1)
// Writes e = mask*exp(logit) to eout + eoutT, plus per-q partial denominators
// (sum of e over this 32-c tile) to denomP[(b,qg,q)][ctile].
// ---------------------------------------------------------------------------
__global__ __launch_bounds__(256) void score_kernel(
    const float* __restrict__ Ec,    // B*CTX*H
    const float* __restrict__ Eqm,   // B*NQ*H
    const float* __restrict__ W_o,   // H
    const float* __restrict__ b_o_p, // scalar
    const float* __restrict__ mask,  // B*CTX
    float* __restrict__ eout,        // B*NQ*CTX
    float* __restrict__ eoutT,       // (B*8qg)*CTX*8
    float* __restrict__ denomP)      // (B*8qg*8q)*16
{
    __shared__ float eqs[8][H_];     // 8 KB
    __shared__ float ecs[32][68];    // 32c x 64h chunk, stride-68 pad (8.5 KB)
    __shared__ float redS[4];

    const int blk = blockIdx.x;
    const int b  = blk & 7;          // XCD swizzle
    const int ctile = (blk >> 3) & 15;
    const int qg = blk >> 7;
    const int t  = threadIdx.x;

    // stage Eq rows (8 q x 256 h), coalesced
    const float* eqb = Eqm + (size_t)(b * NQ_ + qg * 8) * H_;
    #pragma unroll
    for (int i = 0; i < 8; ++i) ((float*)eqs)[t + 256 * i] = eqb[t + 256 * i];

    // Sum(W_o) via butterfly
    float S = W_o[t];
    #pragma unroll
    for (int k = 1; k < 64; k <<= 1) S += __shfl_xor(S, k);
    if ((t & 63) == 0) redS[t >> 6] = S;

    const int cl = t & 31;           // lane's c within 32-c tile
    const int qi = t >> 5;           // thread's q (0..7)
    const int c0 = ctile * 32;
    const float* ec_tile = Ec + (size_t)(b * CTX_ + c0) * H_;
    const int sr = t >> 3, sseg = (t & 7) * 8;      // staging: row, 8-float seg
    const float* ssrc = ec_tile + (size_t)sr * H_ + sseg;
    const float* eqr = eqs[qi];

    float sA = 0.f, sB = 0.f;        // two accumulators: break fma chain
    for (int hb = 0; hb < 4; ++hb) {
        float4 v0 = *(const float4*)(ssrc + hb * 64);
        float4 v1 = *(const float4*)(ssrc + hb * 64 + 4);
        __syncthreads();             // prior chunk's readers done (covers redS/eqs)
        float* dst = &ecs[sr][sseg];
        *(float4*)(dst) = v0; *(float4*)(dst + 4) = v1;
        __syncthreads();
        const int ho = hb * 64;
        #pragma unroll
        for (int h4 = 0; h4 < 16; ++h4) {
            float4 ea = *(const float4*)&ecs[cl][h4 * 4];      // LDS per-lane
            float4 qa = *(const float4*)(eqr + ho + h4 * 4);   // LDS broadcast
            float4 w4 = *(const float4*)(W_o + ho + h4 * 4);   // global uniform
            sA += w4.x * __builtin_amdgcn_rcpf(ea.x * qa.x + 1.f);
            sB += w4.y * __builtin_amdgcn_rcpf(ea.y * qa.y + 1.f);
            sA += w4.z * __builtin_amdgcn_rcpf(ea.z * qa.z + 1.f);
            sB += w4.w * __builtin_amdgcn_rcpf(ea.w * qa.w + 1.f);
        }
    }

    const float base = *b_o_p + redS[0] + redS[1] + redS[2] + redS[3];
    const int c = c0 + cl;
    const float mk = mask[b * CTX_ + c];
    const float e = mk * __expf(base - 2.f * (sA + sB));
    const int q = b * NQ_ + qg * 8 + qi;
    eout[(size_t)q * CTX_ + c] = e;
    eoutT[(((size_t)(b * 8 + qg) * CTX_) + c) * 8 + qi] = e;

    // partial denominator over this 32-c tile (per q): butterfly within 32 lanes
    float d = e;
    d += __shfl_xor(d, 1);  d += __shfl_xor(d, 2);
    d += __shfl_xor(d, 4);  d += __shfl_xor(d, 8);
    d += __shfl_xor(d, 16);
    if (cl == 0)
        denomP[((size_t)((b * 8 + qg) * 8 + qi)) * 16 + ctile] = d;
}

// ---------------------------------------------------------------------------
// Kernel 3: softmax (denom = sum + EPS, reference-exact) + weighted context
// sum. Grid 1024 = b(8) x qgroup(8: 8q) x dq(16: 32d) -> 4 blocks/CU.
// Phase 1: denominators from 16 denomP partials per q (+ wout when dq==0).
// Phase 2: 8 c-groups x 32 d; raw sum, scaled by inv at the end.
// ---------------------------------------------------------------------------
__global__ __launch_bounds__(256) void out_kernel(
    const float* __restrict__ eout,    // B*NQ*CTX
    const float* __restrict__ eoutT,   // (B*8)*CTX*8
    const float* __restrict__ denomP,  // (B*8*8)*16
    const float* __restrict__ context, // B*CTX*DC
    float* __restrict__ out,           // B*NQ*DC
    float* __restrict__ wout)          // B*NQ*CTX
{
    __shared__ float invs[8];
    __shared__ float pc[7][32][8];     // raw partial sums: 7 KB

    const int blk = blockIdx.x;
    const int b  = blk & 7;
    const int qg = (blk >> 3) & 7;
    const int dq = blk >> 6;           // 0..15: d in [dq*32, +32)
    const int t  = threadIdx.x;

    // Phase 1: denominators from partials
    if (t < 8) {
        const float* dp = denomP + ((size_t)((b * 8 + qg) * 8 + t)) * 16;
        float s = EPS_;
        #pragma unroll
        for (int j = 0; j < 16; ++j) s += dp[j];
        invs[t] = 1.f / s;
    }
    __syncthreads();

    if (dq == 0) {                     // wout = e * inv (one block per (b,qg))
        const int qi = t >> 5, cl = t & 31;
        const int q = b * NQ_ + qg * 8 + qi;
        const float inv = invs[qi];
        const float* erow = eout + (size_t)q * CTX_;
        #pragma unroll
        for (int k = 0; k < 16; ++k) {
            const int c = cl + 32 * k;
            wout[(size_t)q * CTX_ + c] = erow[c] * inv;
        }
    }

    // Phase 2: raw weighted sum; cg8 = c-group (64 c), dt = d-lane (32 d)
    const int cg8 = t >> 5;            // 0..7
    const int dt  = t & 31;
    const int d   = dq * 32 + dt;
    const float* cb  = context + ((size_t)(b * CTX_) + cg8 * 64) * DC_ + d;
    const float* eoT = eoutT + (((size_t)(b * 8 + qg) * CTX_) + cg8 * 64) * 8;

    float a0=0,a1=0,a2=0,a3=0,a4=0,a5=0,a6=0,a7=0;
    #pragma unroll 4
    for (int c = 0; c < 64; ++c) {
        const float4 eA = *(const float4*)(eoT + c * 8);      // group-uniform
        const float4 eB = *(const float4*)(eoT + c * 8 + 4);  // group-uniform
        const float v = cb[(size_t)c * DC_];
        a0 += eA.x * v; a1 += eA.y * v; a2 += eA.z * v; a3 += eA.w * v;
        a4 += eB.x * v; a5 += eB.y * v; a6 += eB.z * v; a7 += eB.w * v;
    }
    if (cg8) {
        float* p = pc[cg8 - 1][dt];
        p[0]=a0; p[1]=a1; p[2]=a2; p[3]=a3; p[4]=a4; p[5]=a5; p[6]=a6; p[7]=a7;
    }
    __syncthreads();
    if (cg8 == 0) {
        float r[8] = {a0,a1,a2,a3,a4,a5,a6,a7};
        #pragma unroll
        for (int g = 0; g < 7; ++g)
            #pragma unroll
            for (int j = 0; j < 8; ++j) r[j] += pc[g][dt][j];
        const int qbase = b * NQ_ + qg * 8;
        #pragma unroll
        for (int j = 0; j < 8; ++j)
            out[(size_t)(qbase + j) * DC_ + d] = r[j] * invs[j];
    }
}

extern "C" void kernel_launch(void* const* d_in, const int* in_sizes, int n_in,
                              void* d_out, int out_size, void* d_ws, size_t ws_size,
                              hipStream_t stream) {
    const float* query   = (const float*)d_in[0];  // B,NQ,DQ
    const float* context = (const float*)d_in[1];  // B,CTX,DC
    const float* mask    = (const float*)d_in[2];  // B,CTX
    const float* W_c     = (const float*)d_in[3];  // H,DC
    const float* b_c     = (const float*)d_in[4];  // H
    const float* W_q     = (const float*)d_in[5];  // H,DQ
    const float* W_o     = (const float*)d_in[6];  // H
    const float* b_o     = (const float*)d_in[7];  // scalar

    float* out  = (float*)d_out;                   // B,NQ,DC
    float* wout = out + (size_t)B_ * NQ_ * DC_;    // B,NQ,CTX

    float* Ec     = (float*)d_ws;                      // 4 MB: exp(2*res_c)
    float* Eq     = Ec + (size_t)B_ * CTX_ * H_;       // 512 KB: exp(2*res_q)
    float* eout   = Eq + (size_t)B_ * NQ_ * H_;        // 1 MB
    float* eoutT  = eout + (size_t)B_ * NQ_ * CTX_;    // 1 MB
    float* denomP = eoutT + (size_t)B_ * NQ_ * CTX_;   // 32 KB

    gemm_exp<<<dim3(144, 4), 256, 0, stream>>>(
        context, query, W_c, b_c, W_q, Ec, Eq);
    score_kernel<<<1024, 256, 0, stream>>>(
        Ec, Eq, W_o, b_o, mask, eout, eoutT, denomP);
    out_kernel<<<1024, 256, 0, stream>>>(
        eout, eoutT, denomP, context, out, wout);
}